// Round 4
// baseline (79.174 us; speedup 1.0000x reference)
//
#include <hip/hip_runtime.h>
#include <math.h>
#include <stdint.h>

// Problem constants (b=1, h=8, t=2048, d=64, n=32)
#define BH 8
#define NB 32
#define SS 64
#define DD 64
#define TT 2048

typedef float f32x16 __attribute__((ext_vector_type(16)));
typedef short bf16x8 __attribute__((ext_vector_type(8)));
typedef unsigned short u16;

__device__ __forceinline__ unsigned pkbf(float a, float b) {
  unsigned r;
  asm("v_cvt_pk_bf16_f32 %0, %1, %2" : "=v"(r) : "v"(a), "v"(b));
  return r;
}
__device__ __forceinline__ float exp2x(float x) {
  float r;
  asm("v_exp_f32 %0, %1" : "=v"(r) : "v"(x));
  return r;
}
__device__ __forceinline__ bf16x8 pack8v(const f32x16& v, const int b) {
  union { unsigned u[4]; bf16x8 v8; } x;
  x.u[0] = pkbf(v[b + 0], v[b + 1]);
  x.u[1] = pkbf(v[b + 2], v[b + 3]);
  x.u[2] = pkbf(v[b + 4], v[b + 5]);
  x.u[3] = pkbf(v[b + 6], v[b + 7]);
  return x.v8;
}

// ---------------- Kernel 1: prep (verbatim round-2, verified) -------------
__global__ __launch_bounds__(256) void prep_kernel(
    const float* __restrict__ q, const float* __restrict__ k, const float* __restrict__ v,
    u16* __restrict__ qb, u16* __restrict__ kb, u16* __restrict__ vtb,
    float* __restrict__ qsum, float* __restrict__ ksum)
{
  const int bid = blockIdx.x;
  const int t = threadIdx.x;
  if (bid < 256) {
    __shared__ float vt[SS][68];
    const float* vb = v + (size_t)bid * 4096;
#pragma unroll
    for (int r4 = 0; r4 < 4; ++r4) {
      int f = r4 * 256 + t;
      int row = f >> 4, c4 = (f & 15) << 2;
      *(float4*)&vt[row][c4] = ((const float4*)vb)[f];
    }
    __syncthreads();
    {
      int d = t >> 2;
      int cb = (t & 3) * 2;
      u16* dst = vtb + (size_t)bid * 4096 + d * 64 + cb * 8;
#pragma unroll
      for (int cc = 0; cc < 2; ++cc) {
        int c = cb + cc;
        int s = c >> 1, hi = c & 1;
        int kb0 = 16 * s + 4 * hi;
        uint4 o;
        o.x = pkbf(vt[kb0 + 0][d], vt[kb0 + 1][d]);
        o.y = pkbf(vt[kb0 + 2][d], vt[kb0 + 3][d]);
        o.z = pkbf(vt[kb0 + 8][d], vt[kb0 + 9][d]);
        o.w = pkbf(vt[kb0 + 10][d], vt[kb0 + 11][d]);
        *(uint4*)(dst + cc * 8) = o;
      }
    }
    if (t < 64) {
      const float* qp = q + (size_t)bid * 4096 + t;
      float s = 0.f;
#pragma unroll 8
      for (int r = 0; r < 64; ++r) s += qp[r * 64];
      qsum[bid * 64 + t] = s;
    } else if (t < 128) {
      const float* kp = k + (size_t)bid * 4096 + (t - 64);
      float s = 0.f;
#pragma unroll 8
      for (int r = 0; r < 64; ++r) s += kp[r * 64];
      ksum[bid * 64 + (t - 64)] = s;
    }
  } else {
    const bool isQ = bid < 384;
    const float* src = isQ ? q : k;
    u16* dst = isQ ? qb : kb;
    const float scale = isQ ? 0.18033688011112042f : 1.0f;  // 0.125 * log2(e)
    const int blk = bid - (isQ ? 256 : 384);
#pragma unroll
    for (int it = 0; it < 4; ++it) {
      int chunk = blk * 1024 + it * 256 + t;
      int r = chunk >> 3, sub = chunk & 7;
      int s = sub >> 1, hi = sub & 1;
      const float* ip = src + (size_t)r * 64 + 16 * s + 4 * hi;
      float4 a = *(const float4*)(ip);
      float4 b = *(const float4*)(ip + 8);
      uint4 o;
      o.x = pkbf(a.x * scale, a.y * scale);
      o.y = pkbf(a.z * scale, a.w * scale);
      o.z = pkbf(b.x * scale, b.y * scale);
      o.w = pkbf(b.z * scale, b.w * scale);
      *(uint4*)(dst + (size_t)chunk * 8) = o;
    }
  }
}

// ---------------- Kernel 2: Sinkhorn (verbatim round-2, verified) ---------
__global__ __launch_bounds__(1024) void sinkhorn_kernel(
    const float* __restrict__ qsum, const float* __restrict__ ksum,
    const float* __restrict__ gu, float* __restrict__ Rm)
{
  __shared__ float qs[NB][65];
  __shared__ float ks[NB][65];
  __shared__ float rbuf[NB][33];

  const int bh = blockIdx.x;
  const int t  = threadIdx.x;
  const int i  = t >> 5;
  const int j  = t & 31;

  for (int m = t; m < NB * DD; m += 1024) {
    qs[m >> 6][m & 63] = qsum[bh * 2048 + m];
    ks[m >> 6][m & 63] = ksum[bh * 2048 + m];
  }
  __syncthreads();

  float acc = 0.f;
  for (int e = 0; e < DD; ++e) acc += qs[i][e] * ks[j][e];
  acc *= 0.125f;

  float r = logf(fmaxf(acc, 0.f) + 1e-6f);
  float u = gu[bh * NB * NB + t];
  float g = -logf(-logf(u + 1e-6f) + 1e-6f);
  r = (r + g) * (1.0f / 0.75f);

  for (int it = 0; it < 7; ++it) {
    float m = r;
    m = fmaxf(m, __shfl_xor(m, 16, 32));
    m = fmaxf(m, __shfl_xor(m, 8, 32));
    m = fmaxf(m, __shfl_xor(m, 4, 32));
    m = fmaxf(m, __shfl_xor(m, 2, 32));
    m = fmaxf(m, __shfl_xor(m, 1, 32));
    float s = expf(r - m);
    s += __shfl_xor(s, 16, 32);
    s += __shfl_xor(s, 8, 32);
    s += __shfl_xor(s, 4, 32);
    s += __shfl_xor(s, 2, 32);
    s += __shfl_xor(s, 1, 32);
    r -= m + logf(s);

    rbuf[i][j] = r;
    __syncthreads();
    float cm = -1e30f;
    for (int ii = 0; ii < NB; ++ii) cm = fmaxf(cm, rbuf[ii][j]);
    float cs = 0.f;
    for (int ii = 0; ii < NB; ++ii) cs += expf(rbuf[ii][j] - cm);
    r -= cm + logf(cs);
    __syncthreads();
  }

  float R = expf(r);
  Rm[bh * NB * NB + t] = (R > 1e-3f) ? R : 0.f;
}

// ---------------- Kernel 3: MFMA attention, wave-split q-blocks -----------
// block per (bh,i), bh = bid&7. 512 threads = 8 waves.
// wave w: n = w&1 (q-block of 32 rows), g = w>>1 (j in {g, g+4, ..., g+28}).
// Round-2 math exactly: max-subtracted softmax, per-wave m0/S0/psA,
// per-wave self term U*cacc added before the reduction tree.
__global__ __launch_bounds__(512) void attn_kernel(
    const u16* __restrict__ qb, const u16* __restrict__ kb,
    const u16* __restrict__ vtb, const float* __restrict__ Rm,
    float* __restrict__ out)
{
  __shared__ float redh[2][2][32][68];  // [n][buf][local q-row][d-col]
  __shared__ float cbuf[8][32];

  const int bh  = blockIdx.x & 7;
  const int i   = blockIdx.x >> 3;
  const int t   = threadIdx.x;
  const int w   = t >> 6;
  const int n   = w & 1;
  const int g   = w >> 1;
  const int lane = t & 63;
  const int l31 = lane & 31;
  const int hi  = lane >> 5;

  const u16* qbase = qb + ((size_t)bh * TT + i * SS) * DD;
  const u16* kbh   = kb + (size_t)bh * TT * DD;
  const u16* vbh   = vtb + (size_t)bh * TT * DD;

#define LOADK(dst, base)                                                      \
  {                                                                           \
    _Pragma("unroll") for (int m = 0; m < 2; ++m)                             \
    _Pragma("unroll") for (int s = 0; s < 4; ++s)                             \
      dst[m][s] = *(const bf16x8*)((base) + (l31 + 32 * m) * 64 + 16 * s + 8 * hi); \
  }

  // persistent Q B-fragments for this wave's q-block
  bf16x8 qB[4];
#pragma unroll
  for (int s = 0; s < 4; ++s)
    qB[s] = *(const bf16x8*)(qbase + (32 * n + l31) * 64 + 16 * s + 8 * hi);

  // first j tile (j = g), latency covered by the self phase
  bf16x8 kA[2][4], vB[2][4];
  LOADK(kA, kbh + (size_t)g * SS * DD);
  LOADK(vB, vbh + (size_t)g * SS * DD);

  // ---- self phase: S_self^T block, m0, S0, psA ----
  float m0, S0;
  bf16x8 psA[4];
  {
    const u16* kib = kbh + (size_t)i * SS * DD;
    bf16x8 kAi[2][4];
    LOADK(kAi, kib);
    f32x16 aS0, aS1;
#pragma unroll
    for (int r = 0; r < 16; ++r) { aS0[r] = 0.f; aS1[r] = 0.f; }
#pragma unroll
    for (int s = 0; s < 4; ++s) {
      aS0 = __builtin_amdgcn_mfma_f32_32x32x16_bf16(kAi[0][s], qB[s], aS0, 0, 0, 0);
      aS1 = __builtin_amdgcn_mfma_f32_32x32x16_bf16(kAi[1][s], qB[s], aS1, 0, 0, 0);
    }
    float mx[16];
#pragma unroll
    for (int r = 0; r < 16; ++r) mx[r] = fmaxf(aS0[r], aS1[r]);
#pragma unroll
    for (int off = 8; off > 0; off >>= 1)
#pragma unroll
      for (int r = 0; r < off; ++r) mx[r] = fmaxf(mx[r], mx[r + off]);
    float mm = fmaxf(mx[0], __shfl_xor(mx[0], 32, 64));
#pragma unroll
    for (int r = 0; r < 16; ++r) { aS0[r] = exp2x(aS0[r] - mm); aS1[r] = exp2x(aS1[r] - mm); }
    float sm[16];
#pragma unroll
    for (int r = 0; r < 16; ++r) sm[r] = aS0[r] + aS1[r];
#pragma unroll
    for (int off = 8; off > 0; off >>= 1)
#pragma unroll
      for (int r = 0; r < off; ++r) sm[r] += sm[r + off];
    S0 = sm[0] + __shfl_xor(sm[0], 32, 64);
    m0 = mm;
    psA[0] = pack8v(aS0, 0);
    psA[1] = pack8v(aS0, 8);
    psA[2] = pack8v(aS1, 0);
    psA[3] = pack8v(aS1, 8);
  }

  f32x16 outAcc[2];
#pragma unroll
  for (int nv = 0; nv < 2; ++nv)
#pragma unroll
    for (int e = 0; e < 16; ++e) outAcc[nv][e] = 0.f;
  float cacc = 0.f;
  const float* Rrow = Rm + bh * NB * NB + i * NB;

  // ---- j loop: 8 unconditional iterations ----
#pragma unroll
  for (int jj = 0; jj < 8; ++jj) {
    const int j = g + 4 * jj;
    const float rij = Rrow[j];

    f32x16 a0, a1;
#pragma unroll
    for (int r = 0; r < 16; ++r) { a0[r] = 0.f; a1[r] = 0.f; }
    __builtin_amdgcn_s_setprio(1);
#pragma unroll
    for (int s = 0; s < 4; ++s) {
      a0 = __builtin_amdgcn_mfma_f32_32x32x16_bf16(kA[0][s], qB[s], a0, 0, 0, 0);
      a1 = __builtin_amdgcn_mfma_f32_32x32x16_bf16(kA[1][s], qB[s], a1, 0, 0, 0);
    }
    __builtin_amdgcn_s_setprio(0);

    if (jj < 7) LOADK(kA, kbh + (size_t)(j + 4) * SS * DD);  // kA dead: prefetch

    // softmax over concat [self | cross], round-2 max-subtracted form
    float mx[16];
#pragma unroll
    for (int r = 0; r < 16; ++r) mx[r] = fmaxf(a0[r], a1[r]);
#pragma unroll
    for (int off = 8; off > 0; off >>= 1)
#pragma unroll
      for (int r = 0; r < off; ++r) mx[r] = fmaxf(mx[r], mx[r + off]);
    float mc = fmaxf(mx[0], __shfl_xor(mx[0], 32, 64));
    float mj = fmaxf(m0, mc);
#pragma unroll
    for (int r = 0; r < 16; ++r) { a0[r] = exp2x(a0[r] - mj); a1[r] = exp2x(a1[r] - mj); }
    float sm[16];
#pragma unroll
    for (int r = 0; r < 16; ++r) sm[r] = a0[r] + a1[r];
#pragma unroll
    for (int off = 8; off > 0; off >>= 1)
#pragma unroll
      for (int r = 0; r < off; ++r) sm[r] += sm[r + off];
    float ssum = sm[0] + __shfl_xor(sm[0], 32, 64);
    float e0 = exp2x(m0 - mj);
    float den = S0 * e0 + ssum;
    float inv = rij / den;
    cacc += e0 * inv;
#pragma unroll
    for (int r = 0; r < 16; ++r) { a0[r] *= inv; a1[r] *= inv; }

    __builtin_amdgcn_s_setprio(1);
#pragma unroll
    for (int s = 0; s < 4; ++s) {
      bf16x8 wf = (s < 2) ? pack8v(a0, 8 * (s & 1)) : pack8v(a1, 8 * (s & 1));
      outAcc[0] = __builtin_amdgcn_mfma_f32_32x32x16_bf16(wf, vB[0][s], outAcc[0], 0, 0, 0);
      outAcc[1] = __builtin_amdgcn_mfma_f32_32x32x16_bf16(wf, vB[1][s], outAcc[1], 0, 0, 0);
    }
    __builtin_amdgcn_s_setprio(0);

    if (jj < 7) LOADK(vB, vbh + (size_t)(j + 4) * SS * DD);  // vB dead: prefetch
  }

  // ---- per-wave self term: out += cacc(row) * psA @ V_i ----
  {
    const u16* vib = vbh + (size_t)i * SS * DD;
    bf16x8 vBi[2][4];
    LOADK(vBi, vib);
    f32x16 U[2];
#pragma unroll
    for (int nv = 0; nv < 2; ++nv)
#pragma unroll
      for (int e = 0; e < 16; ++e) U[nv][e] = 0.f;
#pragma unroll
    for (int s = 0; s < 4; ++s) {
      U[0] = __builtin_amdgcn_mfma_f32_32x32x16_bf16(psA[s], vBi[0][s], U[0], 0, 0, 0);
      U[1] = __builtin_amdgcn_mfma_f32_32x32x16_bf16(psA[s], vBi[1][s], U[1], 0, 0, 0);
    }
    if (hi == 0) cbuf[w][l31] = cacc;
    __syncthreads();
#pragma unroll
    for (int r = 0; r < 16; ++r) {
      int row = (r & 3) + 8 * (r >> 2) + 4 * hi;
      float cr = cbuf[w][row];
      outAcc[0][r] += U[0][r] * cr;
      outAcc[1][r] += U[1][r] * cr;
    }
  }

  // ---- per-n 4-wave reduction tree ----
#define RED_W(buf)                                                         \
  {                                                                        \
    _Pragma("unroll") for (int ne = 0; ne < 2; ++ne)                       \
    _Pragma("unroll") for (int r = 0; r < 16; ++r) {                       \
      int row = (r & 3) + 8 * (r >> 2) + 4 * hi;                           \
      (buf)[row][l31 + 32 * ne] = outAcc[ne][r];                           \
    }                                                                      \
  }
#define RED_A(buf)                                                         \
  {                                                                        \
    _Pragma("unroll") for (int ne = 0; ne < 2; ++ne)                       \
    _Pragma("unroll") for (int r = 0; r < 16; ++r) {                       \
      int row = (r & 3) + 8 * (r >> 2) + 4 * hi;                           \
      outAcc[ne][r] += (buf)[row][l31 + 32 * ne];                          \
    }                                                                      \
  }

  if (g >= 2) RED_W(redh[n][g - 2]);
  __syncthreads();
  if (g < 2) RED_A(redh[n][g]);
  __syncthreads();
  if (g == 1) RED_W(redh[n][0]);
  __syncthreads();
  if (g == 0) {
    RED_A(redh[n][0]);
    RED_W(redh[n][0]);
  }
  __syncthreads();

  // coalesced store
  {
    int row = t >> 3;             // global q-row 0..63
    int nr = row >> 5, lrow = row & 31;
    int col0 = (t & 7) * 8;
    float4 a = *(const float4*)&redh[nr][0][lrow][col0];
    float4 b = *(const float4*)&redh[nr][0][lrow][col0 + 4];
    float* ob = out + ((size_t)bh * TT + i * SS + row) * DD + col0;
    *(float4*)ob = a;
    *(float4*)(ob + 4) = b;
  }
#undef LOADK
#undef RED_W
#undef RED_A
}

extern "C" void kernel_launch(void* const* d_in, const int* in_sizes, int n_in,
                              void* d_out, int out_size, void* d_ws, size_t ws_size,
                              hipStream_t stream) {
  (void)in_sizes; (void)n_in; (void)out_size; (void)ws_size;
  const float* q  = (const float*)d_in[0];
  const float* k  = (const float*)d_in[1];
  const float* v  = (const float*)d_in[2];
  const float* gu = (const float*)d_in[3];
  float* out = (float*)d_out;

  char* wsb = (char*)d_ws;
  u16* qb   = (u16*)(wsb);
  u16* kb   = (u16*)(wsb + (1 << 21));
  u16* vtb  = (u16*)(wsb + (2 << 21));
  float* qsum = (float*)(wsb + (3 << 21));
  float* ksum = (float*)(wsb + (3 << 21) + (1 << 16));
  float* Rm   = (float*)(wsb + (3 << 21) + (2 << 16));

  prep_kernel<<<512, 256, 0, stream>>>(q, k, v, qb, kb, vtb, qsum, ksum);
  sinkhorn_kernel<<<BH, 1024, 0, stream>>>(qsum, ksum, gu, Rm);
  attn_kernel<<<BH * NB, 512, 0, stream>>>(qb, kb, vtb, Rm, out);
}

// Round 5
// 59.034 us; speedup vs baseline: 1.3411x; 1.3411x over previous
//
#include <hip/hip_runtime.h>
#include <math.h>
#include <stdint.h>

// Problem constants (b=1, h=8, t=2048, d=64, n=32)
#define BH 8
#define NB 32
#define SS 64
#define DD 64
#define TT 2048

typedef float f32x16 __attribute__((ext_vector_type(16)));
typedef short bf16x8 __attribute__((ext_vector_type(8)));
typedef unsigned short u16;

__device__ __forceinline__ unsigned pkbf(float a, float b) {
  unsigned r;
  asm("v_cvt_pk_bf16_f32 %0, %1, %2" : "=v"(r) : "v"(a), "v"(b));
  return r;
}
__device__ __forceinline__ float exp2x(float x) {
  float r;
  asm("v_exp_f32 %0, %1" : "=v"(r) : "v"(x));
  return r;
}
__device__ __forceinline__ bf16x8 pack8v(const f32x16& v, const int b) {
  union { unsigned u[4]; bf16x8 v8; } x;
  x.u[0] = pkbf(v[b + 0], v[b + 1]);
  x.u[1] = pkbf(v[b + 2], v[b + 3]);
  x.u[2] = pkbf(v[b + 4], v[b + 5]);
  x.u[3] = pkbf(v[b + 6], v[b + 7]);
  return x.v8;
}

// ---------------- Kernel 1: prep — fragment-major bf16 workspace ----------
// One block per tile T = bh*32 + bucket (256 blocks, 256 threads).
// Output layout per tile (4096 u16 = 8KB): chunk c = m*4+s (K/Q rows l31+32m,
// elem-group s) or c = dblk*4+s (V), addr = T*4096 + (c*64 + lane)*8.
// Chunk content (8 u16) is IDENTICAL to round-4's fragment values; only the
// storage address changes so that a wave's fragment load is 1KB contiguous.
__global__ __launch_bounds__(256) void prep_kernel(
    const float* __restrict__ q, const float* __restrict__ k, const float* __restrict__ v,
    u16* __restrict__ qb, u16* __restrict__ kb, u16* __restrict__ vtb,
    float* __restrict__ qsum, float* __restrict__ ksum)
{
  __shared__ float qt[64][68];
  __shared__ float kt[64][68];
  __shared__ float vt[64][68];

  const int T = blockIdx.x;
  const int t = threadIdx.x;
  const float* qsrc = q + (size_t)T * 4096;
  const float* ksrc = k + (size_t)T * 4096;
  const float* vsrc = v + (size_t)T * 4096;

#pragma unroll
  for (int r4 = 0; r4 < 4; ++r4) {
    int f = r4 * 256 + t;
    int row = f >> 4, c4 = (f & 15) << 2;
    *(float4*)&qt[row][c4] = ((const float4*)qsrc)[f];
    *(float4*)&kt[row][c4] = ((const float4*)ksrc)[f];
    *(float4*)&vt[row][c4] = ((const float4*)vsrc)[f];
  }
  __syncthreads();

  const float qscale = 0.18033688011112042f;  // 0.125 * log2(e)

  // q and k chunks: item x (0..511): c = x>>6, lane = x&63
#pragma unroll
  for (int half = 0; half < 2; ++half) {
    int x = half * 256 + t;
    int c = x >> 6, lane = x & 63;
    int l31 = lane & 31, hi = lane >> 5;
    int m = c >> 2, s = c & 3;
    int row = l31 + 32 * m;
    int cb = 16 * s + 4 * hi;
    float4 a = *(const float4*)&qt[row][cb];
    float4 b = *(const float4*)&qt[row][cb + 8];
    uint4 o;
    o.x = pkbf(a.x * qscale, a.y * qscale);
    o.y = pkbf(a.z * qscale, a.w * qscale);
    o.z = pkbf(b.x * qscale, b.y * qscale);
    o.w = pkbf(b.z * qscale, b.w * qscale);
    *(uint4*)(qb + (size_t)T * 4096 + (size_t)x * 8) = o;

    float4 ka = *(const float4*)&kt[row][cb];
    float4 kb4 = *(const float4*)&kt[row][cb + 8];
    uint4 ko;
    ko.x = pkbf(ka.x, ka.y);
    ko.y = pkbf(ka.z, ka.w);
    ko.z = pkbf(kb4.x, kb4.y);
    ko.w = pkbf(kb4.z, kb4.w);
    *(uint4*)(kb + (size_t)T * 4096 + (size_t)x * 8) = ko;

    // v chunks: transposed fragment (row d = l31+32*dblk, k-slots kb0-based)
    int dblk = m;                 // same decomposition of c
    int d = l31 + 32 * dblk;
    int kb0 = 16 * s + 4 * hi;
    uint4 vo;
    vo.x = pkbf(vt[kb0 + 0][d], vt[kb0 + 1][d]);
    vo.y = pkbf(vt[kb0 + 2][d], vt[kb0 + 3][d]);
    vo.z = pkbf(vt[kb0 + 8][d], vt[kb0 + 9][d]);
    vo.w = pkbf(vt[kb0 + 10][d], vt[kb0 + 11][d]);
    *(uint4*)(vtb + (size_t)T * 4096 + (size_t)x * 8) = vo;
  }

  // bucket column sums for the sort-net
  if (t < 64) {
    float s = 0.f;
#pragma unroll 8
    for (int r = 0; r < 64; ++r) s += qt[r][t];
    qsum[T * 64 + t] = s;
  } else if (t < 128) {
    int c = t - 64;
    float s = 0.f;
#pragma unroll 8
    for (int r = 0; r < 64; ++r) s += kt[r][c];
    ksum[T * 64 + c] = s;
  }
}

// ---------------- Kernel 2: Sinkhorn (verbatim round-2/4, verified) -------
__global__ __launch_bounds__(1024) void sinkhorn_kernel(
    const float* __restrict__ qsum, const float* __restrict__ ksum,
    const float* __restrict__ gu, float* __restrict__ Rm)
{
  __shared__ float qs[NB][65];
  __shared__ float ks[NB][65];
  __shared__ float rbuf[NB][33];

  const int bh = blockIdx.x;
  const int t  = threadIdx.x;
  const int i  = t >> 5;
  const int j  = t & 31;

  for (int m = t; m < NB * DD; m += 1024) {
    qs[m >> 6][m & 63] = qsum[bh * 2048 + m];
    ks[m >> 6][m & 63] = ksum[bh * 2048 + m];
  }
  __syncthreads();

  float acc = 0.f;
  for (int e = 0; e < DD; ++e) acc += qs[i][e] * ks[j][e];
  acc *= 0.125f;

  // NOTE: qsum was computed from UNSCALED q (qt holds raw fp32 here), ok.
  float r = logf(fmaxf(acc, 0.f) + 1e-6f);
  float u = gu[bh * NB * NB + t];
  float g = -logf(-logf(u + 1e-6f) + 1e-6f);
  r = (r + g) * (1.0f / 0.75f);

  for (int it = 0; it < 7; ++it) {
    float m = r;
    m = fmaxf(m, __shfl_xor(m, 16, 32));
    m = fmaxf(m, __shfl_xor(m, 8, 32));
    m = fmaxf(m, __shfl_xor(m, 4, 32));
    m = fmaxf(m, __shfl_xor(m, 2, 32));
    m = fmaxf(m, __shfl_xor(m, 1, 32));
    float s = expf(r - m);
    s += __shfl_xor(s, 16, 32);
    s += __shfl_xor(s, 8, 32);
    s += __shfl_xor(s, 4, 32);
    s += __shfl_xor(s, 2, 32);
    s += __shfl_xor(s, 1, 32);
    r -= m + logf(s);

    rbuf[i][j] = r;
    __syncthreads();
    float cm = -1e30f;
    for (int ii = 0; ii < NB; ++ii) cm = fmaxf(cm, rbuf[ii][j]);
    float cs = 0.f;
    for (int ii = 0; ii < NB; ++ii) cs += expf(rbuf[ii][j] - cm);
    r -= cm + logf(cs);
    __syncthreads();
  }

  float R = expf(r);
  Rm[bh * NB * NB + t] = (R > 1e-3f) ? R : 0.f;
}

// ---------------- Kernel 3: MFMA attention (round-4 math, coalesced loads) -
// block per (bh,i), bh = bid&7. 512 threads = 8 waves.
// wave w: n = w&1 (q-block of 32 rows), g = w>>1 (j in {g, g+4, ..., g+28}).
__global__ __launch_bounds__(512) void attn_kernel(
    const u16* __restrict__ qb, const u16* __restrict__ kb,
    const u16* __restrict__ vtb, const float* __restrict__ Rm,
    float* __restrict__ out)
{
  __shared__ float redh[2][2][32][68];
  __shared__ float cbuf[8][32];

  const int bh  = blockIdx.x & 7;
  const int i   = blockIdx.x >> 3;
  const int t   = threadIdx.x;
  const int w   = t >> 6;
  const int n   = w & 1;
  const int g   = w >> 1;
  const int lane = t & 63;
  const int l31 = lane & 31;
  const int hi  = lane >> 5;

  const u16* qtile = qb + ((size_t)(bh * NB + i)) * 4096;
  const u16* kbh   = kb + (size_t)bh * NB * 4096;
  const u16* vbh   = vtb + (size_t)bh * NB * 4096;

  // coalesced fragment load: chunk (m*4+s), 1KB contiguous per instruction
#define LOADK(dst, base)                                                      \
  {                                                                           \
    _Pragma("unroll") for (int m = 0; m < 2; ++m)                             \
    _Pragma("unroll") for (int s = 0; s < 4; ++s)                             \
      dst[m][s] = *(const bf16x8*)((base) + ((size_t)((m * 4 + s) * 64 + lane)) * 8); \
  }

  // persistent Q B-fragments for this wave's q-block
  bf16x8 qB[4];
#pragma unroll
  for (int s = 0; s < 4; ++s)
    qB[s] = *(const bf16x8*)(qtile + ((size_t)((n * 4 + s) * 64 + lane)) * 8);

  // first j tile (j = g), latency covered by the self phase
  bf16x8 kA[2][4], vB[2][4];
  LOADK(kA, kbh + (size_t)g * 4096);
  LOADK(vB, vbh + (size_t)g * 4096);

  // ---- self phase: S_self^T block, m0, S0, psA ----
  float m0, S0;
  bf16x8 psA[4];
  {
    const u16* kib = kbh + (size_t)i * 4096;
    bf16x8 kAi[2][4];
    LOADK(kAi, kib);
    f32x16 aS0, aS1;
#pragma unroll
    for (int r = 0; r < 16; ++r) { aS0[r] = 0.f; aS1[r] = 0.f; }
#pragma unroll
    for (int s = 0; s < 4; ++s) {
      aS0 = __builtin_amdgcn_mfma_f32_32x32x16_bf16(kAi[0][s], qB[s], aS0, 0, 0, 0);
      aS1 = __builtin_amdgcn_mfma_f32_32x32x16_bf16(kAi[1][s], qB[s], aS1, 0, 0, 0);
    }
    float mx[16];
#pragma unroll
    for (int r = 0; r < 16; ++r) mx[r] = fmaxf(aS0[r], aS1[r]);
#pragma unroll
    for (int off = 8; off > 0; off >>= 1)
#pragma unroll
      for (int r = 0; r < off; ++r) mx[r] = fmaxf(mx[r], mx[r + off]);
    float mm = fmaxf(mx[0], __shfl_xor(mx[0], 32, 64));
#pragma unroll
    for (int r = 0; r < 16; ++r) { aS0[r] = exp2x(aS0[r] - mm); aS1[r] = exp2x(aS1[r] - mm); }
    float sm[16];
#pragma unroll
    for (int r = 0; r < 16; ++r) sm[r] = aS0[r] + aS1[r];
#pragma unroll
    for (int off = 8; off > 0; off >>= 1)
#pragma unroll
      for (int r = 0; r < off; ++r) sm[r] += sm[r + off];
    S0 = sm[0] + __shfl_xor(sm[0], 32, 64);
    m0 = mm;
    psA[0] = pack8v(aS0, 0);
    psA[1] = pack8v(aS0, 8);
    psA[2] = pack8v(aS1, 0);
    psA[3] = pack8v(aS1, 8);
  }

  f32x16 outAcc[2];
#pragma unroll
  for (int nv = 0; nv < 2; ++nv)
#pragma unroll
    for (int e = 0; e < 16; ++e) outAcc[nv][e] = 0.f;
  float cacc = 0.f;
  const float* Rrow = Rm + bh * NB * NB + i * NB;

  // ---- j loop: 8 unconditional iterations ----
#pragma unroll
  for (int jj = 0; jj < 8; ++jj) {
    const int j = g + 4 * jj;
    const float rij = Rrow[j];

    f32x16 a0, a1;
#pragma unroll
    for (int r = 0; r < 16; ++r) { a0[r] = 0.f; a1[r] = 0.f; }
    __builtin_amdgcn_s_setprio(1);
#pragma unroll
    for (int s = 0; s < 4; ++s) {
      a0 = __builtin_amdgcn_mfma_f32_32x32x16_bf16(kA[0][s], qB[s], a0, 0, 0, 0);
      a1 = __builtin_amdgcn_mfma_f32_32x32x16_bf16(kA[1][s], qB[s], a1, 0, 0, 0);
    }
    __builtin_amdgcn_s_setprio(0);

    if (jj < 7) LOADK(kA, kbh + (size_t)(j + 4) * 4096);  // kA dead: prefetch

    float mx[16];
#pragma unroll
    for (int r = 0; r < 16; ++r) mx[r] = fmaxf(a0[r], a1[r]);
#pragma unroll
    for (int off = 8; off > 0; off >>= 1)
#pragma unroll
      for (int r = 0; r < off; ++r) mx[r] = fmaxf(mx[r], mx[r + off]);
    float mc = fmaxf(mx[0], __shfl_xor(mx[0], 32, 64));
    float mj = fmaxf(m0, mc);
#pragma unroll
    for (int r = 0; r < 16; ++r) { a0[r] = exp2x(a0[r] - mj); a1[r] = exp2x(a1[r] - mj); }
    float sm[16];
#pragma unroll
    for (int r = 0; r < 16; ++r) sm[r] = a0[r] + a1[r];
#pragma unroll
    for (int off = 8; off > 0; off >>= 1)
#pragma unroll
      for (int r = 0; r < off; ++r) sm[r] += sm[r + off];
    float ssum = sm[0] + __shfl_xor(sm[0], 32, 64);
    float e0 = exp2x(m0 - mj);
    float den = S0 * e0 + ssum;
    float inv = rij / den;
    cacc += e0 * inv;
#pragma unroll
    for (int r = 0; r < 16; ++r) { a0[r] *= inv; a1[r] *= inv; }

    __builtin_amdgcn_s_setprio(1);
#pragma unroll
    for (int s = 0; s < 4; ++s) {
      bf16x8 wf = (s < 2) ? pack8v(a0, 8 * (s & 1)) : pack8v(a1, 8 * (s & 1));
      outAcc[0] = __builtin_amdgcn_mfma_f32_32x32x16_bf16(wf, vB[0][s], outAcc[0], 0, 0, 0);
      outAcc[1] = __builtin_amdgcn_mfma_f32_32x32x16_bf16(wf, vB[1][s], outAcc[1], 0, 0, 0);
    }
    __builtin_amdgcn_s_setprio(0);

    if (jj < 7) LOADK(vB, vbh + (size_t)(j + 4) * 4096);  // vB dead: prefetch
  }

  // ---- per-wave self term: out += cacc(row) * psA @ V_i ----
  {
    const u16* vib = vbh + (size_t)i * 4096;
    bf16x8 vBi[2][4];
    LOADK(vBi, vib);
    f32x16 U[2];
#pragma unroll
    for (int nv = 0; nv < 2; ++nv)
#pragma unroll
      for (int e = 0; e < 16; ++e) U[nv][e] = 0.f;
#pragma unroll
    for (int s = 0; s < 4; ++s) {
      U[0] = __builtin_amdgcn_mfma_f32_32x32x16_bf16(psA[s], vBi[0][s], U[0], 0, 0, 0);
      U[1] = __builtin_amdgcn_mfma_f32_32x32x16_bf16(psA[s], vBi[1][s], U[1], 0, 0, 0);
    }
    if (hi == 0) cbuf[w][l31] = cacc;
    __syncthreads();
#pragma unroll
    for (int r = 0; r < 16; ++r) {
      int row = (r & 3) + 8 * (r >> 2) + 4 * hi;
      float cr = cbuf[w][row];
      outAcc[0][r] += U[0][r] * cr;
      outAcc[1][r] += U[1][r] * cr;
    }
  }

  // ---- per-n 4-wave reduction tree ----
#define RED_W(buf)                                                         \
  {                                                                        \
    _Pragma("unroll") for (int ne = 0; ne < 2; ++ne)                       \
    _Pragma("unroll") for (int r = 0; r < 16; ++r) {                       \
      int row = (r & 3) + 8 * (r >> 2) + 4 * hi;                           \
      (buf)[row][l31 + 32 * ne] = outAcc[ne][r];                           \
    }                                                                      \
  }
#define RED_A(buf)                                                         \
  {                                                                        \
    _Pragma("unroll") for (int ne = 0; ne < 2; ++ne)                       \
    _Pragma("unroll") for (int r = 0; r < 16; ++r) {                       \
      int row = (r & 3) + 8 * (r >> 2) + 4 * hi;                           \
      outAcc[ne][r] += (buf)[row][l31 + 32 * ne];                          \
    }                                                                      \
  }

  if (g >= 2) RED_W(redh[n][g - 2]);
  __syncthreads();
  if (g < 2) RED_A(redh[n][g]);
  __syncthreads();
  if (g == 1) RED_W(redh[n][0]);
  __syncthreads();
  if (g == 0) {
    RED_A(redh[n][0]);
    RED_W(redh[n][0]);
  }
  __syncthreads();

  // coalesced store
  {
    int row = t >> 3;
    int nr = row >> 5, lrow = row & 31;
    int col0 = (t & 7) * 8;
    float4 a = *(const float4*)&redh[nr][0][lrow][col0];
    float4 b = *(const float4*)&redh[nr][0][lrow][col0 + 4];
    float* ob = out + ((size_t)bh * TT + i * SS + row) * DD + col0;
    *(float4*)ob = a;
    *(float4*)(ob + 4) = b;
  }
#undef LOADK
#undef RED_W
#undef RED_A
}

extern "C" void kernel_launch(void* const* d_in, const int* in_sizes, int n_in,
                              void* d_out, int out_size, void* d_ws, size_t ws_size,
                              hipStream_t stream) {
  (void)in_sizes; (void)n_in; (void)out_size; (void)ws_size;
  const float* q  = (const float*)d_in[0];
  const float* k  = (const float*)d_in[1];
  const float* v  = (const float*)d_in[2];
  const float* gu = (const float*)d_in[3];
  float* out = (float*)d_out;

  char* wsb = (char*)d_ws;
  u16* qb   = (u16*)(wsb);
  u16* kb   = (u16*)(wsb + (1 << 21));
  u16* vtb  = (u16*)(wsb + (2 << 21));
  float* qsum = (float*)(wsb + (3 << 21));
  float* ksum = (float*)(wsb + (3 << 21) + (1 << 16));
  float* Rm   = (float*)(wsb + (3 << 21) + (2 << 16));

  prep_kernel<<<256, 256, 0, stream>>>(q, k, v, qb, kb, vtb, qsum, ksum);
  sinkhorn_kernel<<<BH, 1024, 0, stream>>>(qsum, ksum, gu, Rm);
  attn_kernel<<<BH * NB, 512, 0, stream>>>(qb, kb, vtb, Rm, out);
}